// Round 8
// baseline (274.159 us; speedup 1.0000x reference)
//
#include <hip/hip_runtime.h>

// Encoder: 2-layer LSTM (H=16 each), x [B=16384, T=100, I=18], FP32 in/out.
// R14: R6 verbatim (best measured 141.6us) + "parallel-merged" 8-trans cell.
// Model fitting R6-R13: per-SIMD issue port is the wall; trans issue ~32cy
// each (VALUBusy's gfx94x formula undercounts at ~16cy -> the phantom "31%
// idle"). R6 = 420 VALU + 2560 trans + ~144 MFMA ~= 3120cy ~= wall. So:
// cut trans count WITHOUT deepening the graph (R12's common-denominator
// form added 2 levels before each rcp and LOST 550cy to latency):
//   sig(i)*tanh(g) = (gE-1) * rcp((1+aE)(1+gE)),  aE=e^-i, gE=e^{2g}
//   sig(o)*tanh(c) = (cE-1) * rcp((1+dE)(1+cE)),  dE=e^-o, cE=e^{2cc}
//   f-gate keeps its own rcp (feeds c-mul directly).
// 8 trans/cell (5 exp2 + 3 rcp) vs R6's 10; serial depth IDENTICAL to R6
// (exp2 -> add/mul -> rcp -> fma -> exp2 -> rcp -> mul). -16 trans/iter.
// Overflow-hardened: e^{2x} args clamped at 20 (tanh==1.0f in fp32 far
// below; removes the inf*0=NaN hazard R12 merely got away with). Negative
// saturation is clean algebraically (gE->0 gives -sig(i) etc).
// PRECISION: same algebra class as R12 which measured absmax IDENTICAL to
// R6 (0.0009765625 vs 3.9e-3 threshold). Two-term bf16 splits unchanged.
// Everything else R6: one wave per 16-batch tile (1024 waves = 1/SIMD),
// tn-major MFMA chains, packed (hi|lo<<16) h dwords ARE the next step's
// B-fragment, pipeline L1ew -> L2-MFMA -> L1-MFMA(t+1) -> cvt -> load -> L2ew.

typedef float f32x4 __attribute__((ext_vector_type(4)));
typedef __bf16 bf16x8 __attribute__((ext_vector_type(8)));
typedef unsigned int uint32x4 __attribute__((ext_vector_type(4)));

union FragU { bf16x8 v; unsigned short u[8]; unsigned int d[4]; uint32x4 q; };

#define MFMA16(A, B, C) __builtin_amdgcn_mfma_f32_16x16x32_bf16((A), (B), (C), 0, 0, 0)

static __device__ __forceinline__ unsigned short f2bf(float f) {  // RNE (weights)
  unsigned int u = __builtin_bit_cast(unsigned int, f);
  u = u + 0x7FFFu + ((u >> 16) & 1u);
  return (unsigned short)(u >> 16);
}
static __device__ __forceinline__ float bfbits2f(unsigned short h) {
  unsigned int u = ((unsigned int)h) << 16;
  return __builtin_bit_cast(float, u);
}
// 8-trans LSTM cell, R6-depth graph. Returns h, updates c.
static __device__ __forceinline__ float lstm_cell8(float ipre, float fpre,
                                                   float gpre, float opre,
                                                   float& c) {
  const float aE = __builtin_amdgcn_exp2f(ipre * -1.4426950408889634f);  // e^-i
  const float bE = __builtin_amdgcn_exp2f(fpre * -1.4426950408889634f);  // e^-f
  const float gE = __builtin_amdgcn_exp2f(
      fminf(gpre, 20.f) * 2.8853900817779268f);                          // e^{2g}
  const float dE = __builtin_amdgcn_exp2f(opre * -1.4426950408889634f);  // e^-o
  const float fv  = __builtin_amdgcn_rcpf(1.0f + bE);                    // sig(f)
  const float igv = (gE - 1.0f) *
      __builtin_amdgcn_rcpf((1.0f + aE) * (1.0f + gE));  // sig(i)*tanh(g)
  const float cc = fmaf(fv, c, igv);
  c = cc;
  const float cE = __builtin_amdgcn_exp2f(
      fminf(cc, 20.f) * 2.8853900817779268f);                            // e^{2cc}
  return (cE - 1.0f) *
      __builtin_amdgcn_rcpf((1.0f + dE) * (1.0f + cE));  // sig(o)*tanh(cc)
}
// Trunc two-term split packed as (bf_hi | bf_lo<<16), via v_perm_b32:
// D bytes {l[3],l[2],u[3],u[2]} == (u>>16) | (l & 0xFFFF0000). Bit-exact.
static __device__ __forceinline__ unsigned int split_pack(float v) {
  unsigned int u = __builtin_bit_cast(unsigned int, v);
  float hf = __builtin_bit_cast(float, u & 0xFFFF0000u);
  unsigned int l = __builtin_bit_cast(unsigned int, v - hf);
  return __builtin_amdgcn_perm(l, u, 0x07060302u);
}
// Split a float pair into hi-frag dword and lo-frag dword (6 VALU via perm).
static __device__ __forceinline__ void cvt_pair(float f0, float f1,
                                                unsigned int& hd, unsigned int& ld) {
  unsigned int u0 = __builtin_bit_cast(unsigned int, f0);
  unsigned int u1 = __builtin_bit_cast(unsigned int, f1);
  unsigned int h0 = u0 & 0xFFFF0000u;
  unsigned int h1 = u1 & 0xFFFF0000u;
  hd = __builtin_amdgcn_perm(u1, u0, 0x07060302u);
  unsigned int l0 = __builtin_bit_cast(unsigned int, f0 - __builtin_bit_cast(float, h0));
  unsigned int l1 = __builtin_bit_cast(unsigned int, f1 - __builtin_bit_cast(float, h1));
  ld = __builtin_amdgcn_perm(l1, l0, 0x07060302u);
}

struct RawX { float2 a, b2, c, d; };

__global__ __launch_bounds__(256, 1) void enc_kernel(
    const float* __restrict__ x,     // [16384,100,18]
    const float* __restrict__ Wih1,  // [64,18]
    const float* __restrict__ Whh1,  // [64,16]
    const float* __restrict__ bih1,  // [64]
    const float* __restrict__ bhh1,  // [64]
    const float* __restrict__ Wih2,  // [64,16]
    const float* __restrict__ Whh2,  // [64,16]
    const float* __restrict__ bih2,  // [64]
    const float* __restrict__ bhh2,  // [64]
    float* __restrict__ out)         // [16384,16]
{
  const int lane = threadIdx.x & 63;
  const int b    = lane & 15;  // batch in tile: A m-row / B n-col / C col
  const int g    = lane >> 4;  // k-group; C row-quad (units 4g..4g+3)

  const int wid = (int)((blockIdx.x * blockDim.x + threadIdx.x) >> 6);
  const int b0  = wid * 16;

  // ---- loop-invariant weight A-fragments: A[m=lane&15][k=8g+j] ----
  FragU A1h[4], A1l[4], A2h[4], A2l[4], A3h[4], A3l[4], A4h[4], A4l[4];
  f32x4 bias1v[4], bias2v[4];
#pragma unroll
  for (int tn = 0; tn < 4; ++tn) {  // 0=i 1=f 2=g 3=o (PyTorch gate order)
    const int row = tn * 16 + b;
#pragma unroll
    for (int j = 0; j < 8; ++j) {
      const int k = 8 * g + j;
      if (k < 18) {
        const float w = Wih1[row * 18 + k];
        A1h[tn].u[j] = f2bf(w);
        A1l[tn].u[j] = f2bf(w - bfbits2f(A1h[tn].u[j]));
      } else {
        A1h[tn].u[j] = 0;
        A1l[tn].u[j] = 0;
      }
      const int kk = k >> 1;  // hi/lo interleave: both K slots share the weight
      const float w2 = Whh1[row * 16 + kk];
      const float w3 = Wih2[row * 16 + kk];
      const float w4 = Whh2[row * 16 + kk];
      A2h[tn].u[j] = f2bf(w2); A2l[tn].u[j] = f2bf(w2 - bfbits2f(A2h[tn].u[j]));
      A3h[tn].u[j] = f2bf(w3); A3l[tn].u[j] = f2bf(w3 - bfbits2f(A3h[tn].u[j]));
      A4h[tn].u[j] = f2bf(w4); A4l[tn].u[j] = f2bf(w4 - bfbits2f(A4h[tn].u[j]));
    }
#pragma unroll
    for (int r = 0; r < 4; ++r) {
      const int u4 = tn * 16 + 4 * g + r;  // C row = unit 4g+r of gate tn
      bias1v[tn][r] = bih1[u4] + bhh1[u4];
      bias2v[tn][r] = bih2[u4] + bhh2[u4];
    }
  }

  // ---- x addressing: lane (b,g) covers x[b0+b][t][8g .. 8g+7] ----
  // g==3 lanes: k=24..31 are all beyond I=18; their B-slots multiply zero
  // weights (A1 pad), so they read a fixed valid address and never advance.
  const float* const x0 = x + (size_t)(b0 + b) * 1800 + 8 * g;
  const int adv = (g == 3) ? 0 : 18;

  auto loadraw = [&](const float* p) -> RawX {
    RawX r;
    r.a = *(const float2*)p;  // g<2: k 8g..8g+1; g==2: k 16,17; g==3: dummy
    if (g < 2) {              // full 8 features, in-bounds for all t
      r.b2 = *(const float2*)(p + 2);
      r.c  = *(const float2*)(p + 4);
      r.d  = *(const float2*)(p + 6);
    } else {                  // g>=2: only pair a matters (k>=18 hits A-pad)
      r.b2 = r.c = r.d = make_float2(0.f, 0.f);
    }
    return r;
  };
  auto cvt = [&](const RawX& rw_, FragU& hi, FragU& lo) {
    cvt_pair(rw_.a.x, rw_.a.y, hi.d[0], lo.d[0]);
    cvt_pair(rw_.b2.x, rw_.b2.y, hi.d[1], lo.d[1]);
    cvt_pair(rw_.c.x, rw_.c.y, hi.d[2], lo.d[2]);
    cvt_pair(rw_.d.x, rw_.d.y, hi.d[3], lo.d[3]);
  };

  // ---- prologue: raw x for t=0,1,2 in flight together ----
  RawX rw0 = loadraw(x0);
  RawX rw1 = loadraw(x0 + adv);
  RawX rw  = loadraw(x0 + 2 * adv);
  const float* xq = x0 + 3 * adv;  // next load target: t=3

  FragU hb, h2b;
  hb.q  = (uint32x4){0u, 0u, 0u, 0u};  // h1_{-1}
  h2b.q = (uint32x4){0u, 0u, 0u, 0u};  // h2_{-1}
  float c1[4] = {0.f, 0.f, 0.f, 0.f};
  float c2[4] = {0.f, 0.f, 0.f, 0.f};
  float h2v[4] = {0.f, 0.f, 0.f, 0.f};

  FragU xch, xcl;
  cvt(rw0, xch, xcl);  // x(0)

  // ga = L1 gate preacts for t=0 (hb = 0); R6's exact tn-major 5-chain
  f32x4 ga[4];
#pragma unroll
  for (int tn = 0; tn < 4; ++tn) {
    f32x4 acc = MFMA16(A1h[tn].v, xch.v, bias1v[tn]);
    acc = MFMA16(A1l[tn].v, xch.v, acc);
    acc = MFMA16(A1h[tn].v, xcl.v, acc);
    acc = MFMA16(A2h[tn].v, hb.v, acc);
    acc = MFMA16(A2l[tn].v, hb.v, acc);
    ga[tn] = acc;
  }
  cvt(rw1, xch, xcl);  // x(1) ready for the loop's L1-MFMAs(t+1)

#pragma unroll 2
  for (int t = 0; t < 100; ++t) {
    // ---- (1) L1 elementwise (t): ga -> h1(t) as packed hi/lo ----
    FragU rb;
#pragma unroll
    for (int r = 0; r < 4; ++r) {
      const float h = lstm_cell8(ga[0][r], ga[1][r], ga[2][r], ga[3][r], c1[r]);
      const unsigned int pk = split_pack(h);
      hb.d[r] = pk;
      rb.d[r] = (h > 0.f) ? pk : 0u;  // relu: identical split when positive
    }

    // ---- (2) L2 MFMAs (t): uses rb (fresh) and h2b = h2(t-1) ----
    f32x4 gb[4];
#pragma unroll
    for (int tn = 0; tn < 4; ++tn) {
      f32x4 acc = MFMA16(A4h[tn].v, h2b.v, bias2v[tn]);
      acc = MFMA16(A4l[tn].v, h2b.v, acc);
      acc = MFMA16(A3h[tn].v, rb.v, acc);
      acc = MFMA16(A3l[tn].v, rb.v, acc);
      gb[tn] = acc;
    }

    // ---- (3) L1 MFMAs (t+1): independent of gb; hides MFMA latency ----
    f32x4 gan[4];
#pragma unroll
    for (int tn = 0; tn < 4; ++tn) {
      f32x4 acc = MFMA16(A1h[tn].v, xch.v, bias1v[tn]);
      acc = MFMA16(A1l[tn].v, xch.v, acc);
      acc = MFMA16(A1h[tn].v, xcl.v, acc);
      acc = MFMA16(A2h[tn].v, hb.v, acc);
      acc = MFMA16(A2l[tn].v, hb.v, acc);
      gan[tn] = acc;
    }

    // ---- (4) convert x(t+2) from raw regs (loaded 2 iters ago) ----
    FragU nxh, nxl;
    cvt(rw, nxh, nxl);

    // ---- (5) issue raw load x(t+3); uniform guard past the end ----
    RawX rwn = loadraw((t <= 96) ? xq : x0);
    xq += adv;

    // ---- (6) L2 elementwise (t): gb arrived long ago ----
#pragma unroll
    for (int r = 0; r < 4; ++r) {
      const float h = lstm_cell8(gb[0][r], gb[1][r], gb[2][r], gb[3][r], c2[r]);
      h2v[r] = h;
      h2b.d[r] = split_pack(h);
    }

    // rotate pipeline registers (elided by unroll-2 ping-pong)
#pragma unroll
    for (int tn = 0; tn < 4; ++tn) ga[tn] = gan[tn];
    xch = nxh;
    xcl = nxl;
    rw = rwn;
  }

  // ---- output: relu(h2_last); lane (b,g) holds units 4g..4g+3 of batch b ----
  f32x4 o;
#pragma unroll
  for (int r = 0; r < 4; ++r) o[r] = fmaxf(h2v[r], 0.f);
  *(f32x4*)(out + (size_t)(b0 + b) * 16 + 4 * g) = o;  // 16B-aligned

  (void)x0;
}

extern "C" void kernel_launch(void* const* d_in, const int* in_sizes, int n_in,
                              void* d_out, int out_size, void* d_ws, size_t ws_size,
                              hipStream_t stream) {
  (void)in_sizes; (void)n_in; (void)d_ws; (void)ws_size; (void)out_size;
  // 16384 batch / 16 per wave / 4 waves per block = 256 blocks (1 per CU).
  enc_kernel<<<dim3(256), dim3(256), 0, stream>>>(
      (const float*)d_in[0],
      (const float*)d_in[1],
      (const float*)d_in[2],
      (const float*)d_in[3],
      (const float*)d_in[4],
      (const float*)d_in[5],
      (const float*)d_in[6],
      (const float*)d_in[7],
      (const float*)d_in[8],
      (float*)d_out);
}